// Round 5
// baseline (6030.870 us; speedup 1.0000x reference)
//
#include <hip/hip_runtime.h>
#include <hip/hip_cooperative_groups.h>
#include <math.h>

namespace cg = cooperative_groups;

#define S_LEN 16
#define BSZ   64
#define NN    10000
#define LAT   128
#define DH    257
#define KTAB  1024
#define CSTRIDE (KTAB + 8)    // costab leading dim (mult of 4)
#define FSTRIDE (KTAB + 4)    // ftab leading dim (mult of 4)
#define NTILE 64
#define NTILES 157            // ceil(10000/64)
#define SCALE 0.08838834764831845f
#define NEG1E9 -1000000000.0f
#define GRID_BLOCKS 256
#define BLOCK_THREADS 512
#define GSTRIDE (GRID_BLOCKS * BLOCK_THREADS)

// ---------------- combine partials over tiles -> logit (tid<64) ----------------
__device__ void do_combine(const float* __restrict__ partials, const float* __restrict__ vconst,
                           float* __restrict__ out, int ps, int tid) {
    if (tid >= 64) return;
    int b = tid;
    float M = -3.0e38f, D = 0.f, Nm = 0.f;
    const float4* pp = (const float4*)partials + b * NTILES;
    for (int i = 0; i < NTILES; ++i) {
        float4 p = pp[i];
        float M2 = fmaxf(M, p.x);
        float e1 = __expf(M - M2), e2 = __expf(p.x - M2);
        D = D * e1 + p.y * e2;
        Nm = Nm * e1 + p.z * e2;
        M = M2;
    }
    out[ps * BSZ + b] = Nm / D + vconst[0];
}

// ---------------- GRU one row, 256 threads (tid2 in [0,256)), sm: 1028 floats ----------------
__device__ void do_gru_row256(int r, int tid2, int s,
    const float* __restrict__ x, const float* __restrict__ t,
    const int* __restrict__ source, const int* __restrict__ target,
    const float* __restrict__ tw, const float* __restrict__ tb_,
    const float* __restrict__ W_ihT, const float* __restrict__ W_hhT,
    const float* __restrict__ b_ih, const float* __restrict__ b_hh,
    const float* __restrict__ mem, float* __restrict__ newh, float* sm) {
    float* msg = sm;          // 132
    float* h   = sm + 132;    // 128
    float* gi3 = sm + 260;    // 384
    float* gh3 = sm + 644;    // 384
    int b = r & 63;
    int idx = (r < 64) ? source[s * BSZ + b] : target[s * BSZ + b];
    const float* xs = x + (size_t)(s * BSZ + b) * NN;
    const float* ts = t + (size_t)(s * BSZ + b) * NN;
    if (tid2 == 0) msg[0] = xs[idx];
    if (tid2 < 128) {
        float tv = ts[idx];
        msg[1 + tid2] = __cosf(tv * tw[tid2] + tb_[tid2]);
        h[tid2] = mem[(size_t)idx * LAT + tid2];
    }
    __syncthreads();
    if (tid2 < 128) {
        int j = tid2;
        float a0 = b_ih[j], a1 = b_ih[128 + j], a2 = b_ih[256 + j];
#pragma unroll 4
        for (int d = 0; d < 129; ++d) {
            float m = msg[d];
            const float* col = W_ihT + d * 384;
            a0 += m * col[j]; a1 += m * col[128 + j]; a2 += m * col[256 + j];
        }
        gi3[j] = a0; gi3[128 + j] = a1; gi3[256 + j] = a2;
    } else {
        int j = tid2 - 128;
        float a0 = b_hh[j], a1 = b_hh[128 + j], a2 = b_hh[256 + j];
#pragma unroll 4
        for (int l = 0; l < 128; ++l) {
            float hv = h[l];
            const float* col = W_hhT + l * 384;
            a0 += hv * col[j]; a1 += hv * col[128 + j]; a2 += hv * col[256 + j];
        }
        gh3[j] = a0; gh3[128 + j] = a1; gh3[256 + j] = a2;
    }
    __syncthreads();
    if (tid2 < 128) {
        int j = tid2;
        float rr = 1.f / (1.f + __expf(-(gi3[j] + gh3[j])));
        float zz = 1.f / (1.f + __expf(-(gi3[128 + j] + gh3[128 + j])));
        float nn2 = tanhf(gi3[256 + j] + rr * gh3[256 + j]);
        newh[r * LAT + j] = (1.f - zz) * nn2 + zz * h[j];
    }
}

// ---------------- parallel last-writer-wins scatter (512 threads) ----------------
__device__ void do_scatter(int tid, int s, const int* __restrict__ source,
                           const int* __restrict__ target, const float* __restrict__ newh,
                           float* __restrict__ mem, float* sm) {
    int* idxs = (int*)sm;
    int* alive = idxs + 128;
    if (tid < 128) idxs[tid] = (tid < 64) ? source[s * BSZ + tid] : target[s * BSZ + (tid - 64)];
    __syncthreads();
    if (tid < 128) {
        int i2 = idxs[tid];
        int a = 1;
        for (int r2 = tid + 1; r2 < 128; ++r2)
            if (idxs[r2] == i2) { a = 0; break; }
        alive[tid] = a;
    }
    __syncthreads();
    int row = tid >> 2, q4 = tid & 3;   // 4 threads/row, 32 floats each
    if (alive[row]) {
        const float4* srcp = (const float4*)(newh + row * LAT + q4 * 32);
        float4* dstp = (float4*)(mem + (size_t)idxs[row] * LAT + q4 * 32);
#pragma unroll
        for (int j = 0; j < 8; ++j) dstp[j] = srcp[j];
    }
}

// ---------------- mid per-b: q, u, qbk, ftab (512 threads), sm: 4624 floats ----------------
__device__ void do_mid(int b, int tid, int s,
    const float* __restrict__ x, const int* __restrict__ source, const int* __restrict__ target,
    const float* __restrict__ tb_, const float* __restrict__ Wq, const float* __restrict__ bq,
    const float* __restrict__ WkT, const float* __restrict__ bk,
    const float* __restrict__ newh, float* __restrict__ u0_g, float* __restrict__ qbk_g,
    float* __restrict__ uT, float* __restrict__ ftab, const float* __restrict__ costab,
    float* sm) {
    float* th    = sm;         // 260 (pad to 264)
    float* q_s   = sm + 264;   // 128
    float* red   = sm + 392;   // 512
    float* upart = sm + 904;   // 514 (pad to 516)
    float* udt_s = sm + 1420;  // 128
    float* fpart = sm + 1548;  // 3072
    int* s_lastp = (int*)(sm + 4620);
    if (tid < 64) {
        unsigned long long mball = __ballot(target[s * BSZ + tid] == target[s * BSZ + b]);
        if (tid == 0) *s_lastp = 63 - __builtin_clzll(mball);
    }
    if (tid == 256) th[0] = x[(size_t)(s * BSZ + b) * NN + target[s * BSZ + b]];
    if (tid >= 384) th[129 + (tid - 384)] = __cosf(tb_[tid - 384]);
    __syncthreads();
    if (tid < 128) th[1 + tid] = newh[(64 + *s_lastp) * LAT + tid];   // post-scatter mem[tg]
    __syncthreads();
    {   // q: K split 4 ways
        int l = tid & 127, kc = tid >> 7;
        int d0 = (kc * 257) >> 2, d1 = ((kc + 1) * 257) >> 2;
        float a = 0.f;
#pragma unroll 4
        for (int d = d0; d < d1; ++d) a += th[d] * Wq[d * LAT + l];
        red[tid] = a;
    }
    __syncthreads();
    if (tid < 128) q_s[tid] = bq[tid] + red[tid] + red[128 + tid] + red[256 + tid] + red[384 + tid];
    __syncthreads();
    if (tid < 64) {   // qbk = q . bk
        float a = bk[tid] * q_s[tid] + bk[64 + tid] * q_s[64 + tid];
        for (int off = 32; off; off >>= 1) a += __shfl_down(a, off, 64);
        if (tid == 0) qbk_g[b] = a;
    }
    {   // u[d] = sum_j WkT[j][d] * q[j], K split 2 ways
        int dd = tid & 255, kc = tid >> 8;
        int j0 = kc * 64;
        for (int d = dd; d < 257; d += 256) {
            float a = 0.f;
#pragma unroll 4
            for (int j = j0; j < j0 + 64; ++j) a += WkT[j * 260 + d] * q_s[j];
            upart[kc * 257 + d] = a;
        }
    }
    __syncthreads();
    if (tid < 257) {
        float a = upart[tid] + upart[257 + tid];
        if (tid == 0) u0_g[b] = a;
        else if (tid <= 128) uT[(tid - 1) * BSZ + b] = a;
        else udt_s[tid - 129] = a;
    }
    __syncthreads();
    {   // ftab: 8 points/thread, L split 4 ways
        int pi = tid & 127, lc = tid >> 7;
        int l0 = lc * 32;
        float a0x = 0.f, a0y = 0.f, a0z = 0.f, a0w = 0.f;
        float a1x = 0.f, a1y = 0.f, a1z = 0.f, a1w = 0.f;
#pragma unroll 4
        for (int l = l0; l < l0 + 32; ++l) {
            float ul = udt_s[l];
            const float* cp = &costab[l * CSTRIDE + pi * 8];
            float4 c0 = *(const float4*)cp;
            float4 c1 = *(const float4*)(cp + 4);
            a0x += ul * c0.x; a0y += ul * c0.y; a0z += ul * c0.z; a0w += ul * c0.w;
            a1x += ul * c1.x; a1y += ul * c1.y; a1z += ul * c1.z; a1w += ul * c1.w;
        }
        if (lc) {
            float* fp = &fpart[(lc - 1) * 1024 + pi * 8];
            *(float4*)fp = make_float4(a0x, a0y, a0z, a0w);
            *(float4*)(fp + 4) = make_float4(a1x, a1y, a1z, a1w);
        }
        if (pi == 127) {
            float a = 0.f;
            for (int l = l0; l < l0 + 32; ++l) a += udt_s[l] * costab[l * CSTRIDE + KTAB];
            red[lc] = a;
        }
        __syncthreads();
        if (lc == 0) {
            for (int c = 0; c < 3; ++c) {
                const float* fp = &fpart[c * 1024 + pi * 8];
                a0x += fp[0]; a0y += fp[1]; a0z += fp[2]; a0w += fp[3];
                a1x += fp[4]; a1y += fp[5]; a1z += fp[6]; a1w += fp[7];
            }
            float* fo = &ftab[b * FSTRIDE + pi * 8];
            *(float4*)fo = make_float4(a0x, a0y, a0z, a0w);
            *(float4*)(fo + 4) = make_float4(a1x, a1y, a1z, a1w);
        }
        if (tid == 0) ftab[b * FSTRIDE + KTAB] = red[0] + red[1] + red[2] + red[3];
    }
}

// ---------------- fused attn tile (512 threads), sm: 9280 floats ----------------
__device__ void do_attn512(int tile, int tid, int s,
    const float* __restrict__ x, const float* __restrict__ t,
    const void* __restrict__ maskp, const int* __restrict__ modep,
    const float* __restrict__ mem, const float* __restrict__ uT,
    const float* __restrict__ u0_g, const float* __restrict__ qbk_g,
    const float* __restrict__ ftab, const float* __restrict__ gtab,
    const float* __restrict__ wv_out, float* __restrict__ partials, float* sm) {
    int n0 = tile * NTILE;
    int tb2 = tid >> 4, tn = tid & 15;     // tb2 0..31, covers b in pairs
    float* memT   = sm;          // 64*72 = 4608
    float* uTs    = sm + 4608;   // 64*68 = 4352
    float* wv_s   = sm + 8960;   // 128
    float* memv_s = sm + 9088;   // 64
    float* u0_s   = sm + 9152;   // 64
    float* qbk_s  = sm + 9216;   // 64
    int nvalid = NN - n0; if (nvalid > NTILE) nvalid = NTILE;

    if (tid < 128) wv_s[tid] = wv_out[1 + tid];
    else if (tid < 192) { int i = tid - 128; u0_s[i] = u0_g[i]; }
    else if (tid < 256) { int i = tid - 192; qbk_s[i] = qbk_g[i]; }
    else if (tid < 320) memv_s[tid - 256] = 0.f;

    float acc[2][4];
#pragma unroll
    for (int i = 0; i < 2; ++i)
#pragma unroll
        for (int j = 0; j < 4; ++j) acc[i][j] = 0.f;

    for (int l0 = 0; l0 < 128; l0 += 64) {
        __syncthreads();
        {   // stage mem -> memT transposed: 8 l's per thread
            int n_l = tid & 63, lq = (tid >> 6) * 8;
            if (n_l < nvalid) {
                const float* mrow = mem + (size_t)(n0 + n_l) * LAT + l0 + lq;
                float4 a0 = *(const float4*)(mrow + 0);
                float4 a1 = *(const float4*)(mrow + 4);
                memT[(lq + 0) * 72 + n_l] = a0.x; memT[(lq + 1) * 72 + n_l] = a0.y;
                memT[(lq + 2) * 72 + n_l] = a0.z; memT[(lq + 3) * 72 + n_l] = a0.w;
                memT[(lq + 4) * 72 + n_l] = a1.x; memT[(lq + 5) * 72 + n_l] = a1.y;
                memT[(lq + 6) * 72 + n_l] = a1.z; memT[(lq + 7) * 72 + n_l] = a1.w;
            } else {
#pragma unroll
                for (int j = 0; j < 8; ++j) memT[(lq + j) * 72 + n_l] = 0.f;
            }
        }
        {   // stage uT chunk: 8 b's per thread
            int l = tid >> 3, b8 = (tid & 7) * 8;
            const float* up = &uT[(l0 + l) * BSZ + b8];
            float4 v0 = *(const float4*)up;
            float4 v1 = *(const float4*)(up + 4);
            float* dst = &uTs[l * 68 + b8];
            *(float4*)dst = v0;
            *(float4*)(dst + 4) = v1;
        }
        __syncthreads();
        if (tid < 64) {   // memv partial
            float a = memv_s[tid];
            for (int l = 0; l < 64; ++l) a += wv_s[l0 + l] * memT[l * 72 + tid];
            memv_s[tid] = a;
        }
        for (int l = 0; l < 64; ++l) {
            float2 uv = *(const float2*)&uTs[l * 68 + tb2 * 2];
            float4 mv = *(const float4*)&memT[l * 72 + tn * 4];
            acc[0][0] += uv.x * mv.x; acc[0][1] += uv.x * mv.y; acc[0][2] += uv.x * mv.z; acc[0][3] += uv.x * mv.w;
            acc[1][0] += uv.y * mv.x; acc[1][1] += uv.y * mv.y; acc[1][2] += uv.y * mv.z; acc[1][3] += uv.y * mv.w;
        }
    }
    __syncthreads();

    const float c0 = wv_out[0];
    int mode = *modep;
    const int* m32 = (const int*)maskp;
    const unsigned char* m8 = (const unsigned char*)maskp;
    const float* mf = (const float*)maskp;

    float pm[2], pd[2], pn[2];
#pragma unroll
    for (int i = 0; i < 2; ++i) { pm[i] = -3.0e38f; pd[i] = 0.f; pn[i] = 0.f; }

    for (int i = 0; i < 2; ++i) {
        int b = tb2 * 2 + i;
        size_t base = (size_t)(s * BSZ + b) * NN + n0 + tn * 4;
        float xv4[4], tv4[4]; int msk[4], vld[4];
        if (tn * 4 + 3 < nvalid) {
            float4 xx = *(const float4*)(x + base);
            float4 tt = *(const float4*)(t + base);
            xv4[0] = xx.x; xv4[1] = xx.y; xv4[2] = xx.z; xv4[3] = xx.w;
            tv4[0] = tt.x; tv4[1] = tt.y; tv4[2] = tt.z; tv4[3] = tt.w;
            if (mode == 1) {
                unsigned mw = *(const unsigned*)(m8 + base);
                msk[0] = mw & 0xff; msk[1] = (mw >> 8) & 0xff; msk[2] = (mw >> 16) & 0xff; msk[3] = (mw >> 24) & 0xff;
            } else if (mode == 2) {
                float4 mm = *(const float4*)(mf + base);
                msk[0] = (mm.x != 0.f); msk[1] = (mm.y != 0.f); msk[2] = (mm.z != 0.f); msk[3] = (mm.w != 0.f);
            } else {
                int4 mm = *(const int4*)(m32 + base);
                msk[0] = mm.x; msk[1] = mm.y; msk[2] = mm.z; msk[3] = mm.w;
            }
            vld[0] = vld[1] = vld[2] = vld[3] = 1;
        } else {
            for (int j = 0; j < 4; ++j) {
                int n = tn * 4 + j;
                vld[j] = (n < nvalid);
                if (vld[j]) {
                    xv4[j] = x[base + j]; tv4[j] = t[base + j];
                    msk[j] = (mode == 1) ? (int)m8[base + j] : (mode == 2) ? (mf[base + j] != 0.f) : m32[base + j];
                } else { xv4[j] = 0.f; tv4[j] = 0.f; msk[j] = 0; }
            }
        }
        const float* ft = ftab + b * FSTRIDE;
#pragma unroll
        for (int j = 0; j < 4; ++j) {
            if (!vld[j]) continue;
            float xv = xv4[j], tv = tv4[j];
            float p = tv * (float)KTAB;
            p = fminf(fmaxf(p, 0.f), (float)KTAB - 0.001f);
            int ii = (int)p;
            float fr = p - (float)ii;
            float f0 = ft[ii];
            float fv = f0 + (ft[ii + 1] - f0) * fr;
            float g0 = gtab[ii];
            float gv = g0 + (gtab[ii + 1] - g0) * fr;
            float sc = SCALE * (xv * u0_s[b] + acc[i][j] + fv + qbk_s[b]);
            if (msk[j] == 0) sc = NEG1E9;
            float val = xv * c0 + memv_s[tn * 4 + j] + gv;
            if (sc > pm[i]) {
                float a = __expf(pm[i] - sc);
                pd[i] = pd[i] * a + 1.f;
                pn[i] = pn[i] * a + val;
                pm[i] = sc;
            } else {
                float e = __expf(sc - pm[i]);
                pd[i] += e;
                pn[i] += e * val;
            }
        }
    }
#pragma unroll
    for (int mk2 = 1; mk2 < 16; mk2 <<= 1) {
#pragma unroll
        for (int i = 0; i < 2; ++i) {
            float mo = __shfl_xor(pm[i], mk2);
            float d2 = __shfl_xor(pd[i], mk2);
            float n2 = __shfl_xor(pn[i], mk2);
            float M = fmaxf(pm[i], mo);
            float e1 = __expf(pm[i] - M), e2 = __expf(mo - M);
            pd[i] = pd[i] * e1 + d2 * e2;
            pn[i] = pn[i] * e1 + n2 * e2;
            pm[i] = M;
        }
    }
    if (tn == 0) {
#pragma unroll
        for (int i = 0; i < 2; ++i) {
            int b = tb2 * 2 + i;
            *(float4*)&partials[(size_t)(b * NTILES + tile) * 4] = make_float4(pm[i], pd[i], pn[i], 0.f);
        }
    }
}

// ---------------- mask dtype detector ----------------
__device__ void do_detect(int tid, const int* __restrict__ mask, int* __restrict__ modep, float* sm) {
    int* hasHigh = (int*)sm;
    int* hasFloat = hasHigh + 1;
    if (tid == 0) { *hasHigh = 0; *hasFloat = 0; }
    __syncthreads();
    for (int i = tid; i < 4096; i += BLOCK_THREADS) {
        int v = mask[i];
        if ((unsigned)v > 1u) atomicOr(hasHigh, 1);
        if (v == 0x3F800000) atomicOr(hasFloat, 1);
    }
    __syncthreads();
    if (tid == 0) *modep = *hasFloat ? 2 : (*hasHigh ? 1 : 0);
}

// ---------------- the persistent cooperative kernel ----------------
__global__ void __launch_bounds__(BLOCK_THREADS)
mega_kernel(const float* __restrict__ x, const float* __restrict__ t,
            const int* __restrict__ source, const int* __restrict__ target,
            const void* __restrict__ maskp,
            const float* __restrict__ tw, const float* __restrict__ tb_,
            const float* __restrict__ W_ih, const float* __restrict__ W_hh,
            const float* __restrict__ b_ih, const float* __restrict__ b_hh,
            const float* __restrict__ Wq, const float* __restrict__ bq,
            const float* __restrict__ Wk, const float* __restrict__ bk,
            const float* __restrict__ Wv, const float* __restrict__ bv,
            const float* __restrict__ W_out, const float* __restrict__ b_out,
            float* __restrict__ ws, float* __restrict__ out) {
    __shared__ __align__(16) float sm[9280];
    cg::grid_group grid = cg::this_grid();
    int blk = blockIdx.x, tid = threadIdx.x;
    int gtid = blk * BLOCK_THREADS + tid;

    float* mem      = ws;                    // 1,280,000
    float* newh     = mem + 1280000;         // 16,384
    float* uT       = newh + 16384;          // 8,192
    float* u0_g     = uT + 8192;             // 64
    float* qbk_g    = u0_g + 64;             // 64
    float* ftab     = qbk_g + 64;            // 64*1028 = 65,792
    float* gtab     = ftab + 65792;          // 1,028
    float* costab   = gtab + 1028;           // 128*1032 = 132,096
    float* partials = costab + 132096;       // 64*157*4 = 40,192
    float* wv_out   = partials + 40192;      // 260
    float* vconst   = wv_out + 260;          // 4
    float* W_ihT    = vconst + 4;            // 49,536
    float* W_hhT    = W_ihT + 49536;         // 49,152
    float* WkT      = W_hhT + 49152;         // 33,280
    int*   modep    = (int*)(WkT + 33280);

    // ---- P0: zero mem, transposes, costab, setup1, detect ----
    for (int i = gtid; i < (NN * LAT) / 4; i += GSTRIDE)
        ((float4*)mem)[i] = make_float4(0.f, 0.f, 0.f, 0.f);
    for (int i = gtid; i < 129 * 384; i += GSTRIDE) { int d = i / 384, j = i % 384; W_ihT[i] = W_ih[j * 129 + d]; }
    for (int i = gtid; i < 128 * 384; i += GSTRIDE) { int l = i / 384, j = i % 384; W_hhT[i] = W_hh[j * 128 + l]; }
    for (int i = gtid; i < 128 * 260; i += GSTRIDE) { int j = i / 260, d = i % 260; WkT[i] = (d < 257) ? Wk[d * 128 + j] : 0.f; }
    for (int p = gtid; p <= KTAB; p += GSTRIDE) {
        float tv = (float)p * (1.0f / KTAB);
        for (int l = 0; l < 128; ++l) costab[l * CSTRIDE + p] = __cosf(tv * tw[l] + tb_[l]);
    }
    if (blk == 255) {
        if (tid < DH) {
            float a = 0.f;
            for (int j = 0; j < LAT; ++j) a += Wv[tid * LAT + j] * W_out[j];
            wv_out[tid] = a;
        }
        if (tid == 0) {
            float a = b_out[0];
            for (int j = 0; j < LAT; ++j) a += bv[j] * W_out[j];
            *vconst = a;
        }
    }
    if (blk == 254) do_detect(tid, (const int*)maskp, modep, sm);
    grid.sync();

    // ---- P0b: gtab + gru(0) ----
    if (blk < 2) {
        int p = blk * BLOCK_THREADS + tid;
        if (p <= KTAB) {
            float a = 0.f;
            for (int l = 0; l < 128; ++l) a += wv_out[129 + l] * costab[l * CSTRIDE + p];
            gtab[p] = a;
        }
    } else if (blk >= 2 && blk < 66) {
        int r0 = (blk - 2) * 2, half = tid >> 8;
        do_gru_row256(r0 + half, tid & 255, 0, x, t, source, target, tw, tb_,
                      W_ihT, W_hhT, b_ih, b_hh, mem, newh, sm + half * 1028);
    }
    grid.sync();

    // ---- main loop: P1 = {mid || scatter || combine(s-1)}, P2 = {attn || gru(s+1)} ----
    for (int s = 0; s < S_LEN; ++s) {
        if (blk < 64)
            do_mid(blk, tid, s, x, source, target, tb_, Wq, bq, WkT, bk,
                   newh, u0_g, qbk_g, uT, ftab, costab, sm);
        else if (blk == 64)
            do_scatter(tid, s, source, target, newh, mem, sm);
        else if (blk == 65 && s > 0)
            do_combine(partials, vconst, out, s - 1, tid);
        grid.sync();

        if (blk < NTILES)
            do_attn512(blk, tid, s, x, t, maskp, modep, mem, uT, u0_g, qbk_g,
                       ftab, gtab, wv_out, partials, sm);
        else if (s < S_LEN - 1 && blk >= NTILES && blk < NTILES + 64) {
            int r0 = (blk - NTILES) * 2, half = tid >> 8;
            do_gru_row256(r0 + half, tid & 255, s + 1, x, t, source, target, tw, tb_,
                          W_ihT, W_hhT, b_ih, b_hh, mem, newh, sm + half * 1028);
        }
        grid.sync();
    }
    if (blk == 65) do_combine(partials, vconst, out, S_LEN - 1, tid);
}

extern "C" void kernel_launch(void* const* d_in, const int* in_sizes, int n_in,
                              void* d_out, int out_size, void* d_ws, size_t ws_size,
                              hipStream_t stream) {
    const float* x      = (const float*)d_in[0];
    const float* t      = (const float*)d_in[1];
    const int*   source = (const int*)d_in[2];
    const int*   target = (const int*)d_in[3];
    const void*  maskp  = (const void*)d_in[4];
    const float* tw     = (const float*)d_in[5];
    const float* tb     = (const float*)d_in[6];
    const float* W_ih   = (const float*)d_in[7];
    const float* W_hh   = (const float*)d_in[8];
    const float* b_ih   = (const float*)d_in[9];
    const float* b_hh   = (const float*)d_in[10];
    const float* Wq     = (const float*)d_in[11];
    const float* bq     = (const float*)d_in[12];
    const float* Wk     = (const float*)d_in[13];
    const float* bk     = (const float*)d_in[14];
    const float* Wv     = (const float*)d_in[15];
    const float* bv     = (const float*)d_in[16];
    const float* W_out  = (const float*)d_in[17];
    const float* b_out  = (const float*)d_in[18];
    float* ws  = (float*)d_ws;
    float* out = (float*)d_out;

    void* kargs[] = { (void*)&x, (void*)&t, (void*)&source, (void*)&target, (void*)&maskp,
                      (void*)&tw, (void*)&tb, (void*)&W_ih, (void*)&W_hh, (void*)&b_ih,
                      (void*)&b_hh, (void*)&Wq, (void*)&bq, (void*)&Wk, (void*)&bk,
                      (void*)&Wv, (void*)&bv, (void*)&W_out, (void*)&b_out,
                      (void*)&ws, (void*)&out };
    hipLaunchCooperativeKernel((void*)mega_kernel, dim3(GRID_BLOCKS), dim3(BLOCK_THREADS),
                               kargs, 0, stream);
}